// Round 11
// baseline (276.897 us; speedup 1.0000x reference)
//
#include <hip/hip_runtime.h>
#include <hip/hip_bf16.h>

// y = (softmax((xWq)(xWk)^T/8) + B) @ (xWv); b=2 s=2048 d=1024 h=16 hd=64
// conv_x -> wtrans -> qkv_gemm (R7 m97 128^2, V pre-transposed) -> attn
// attn R11 = R7 + COALESCED bias loads (4 rows x 256B contiguous per instr)
//   bounced through per-wave LDS (cvt_pk + ds_write_b64 swizzled, ds_read_b128
//   back in A-frag layout). Tests the L2-transaction-rate theory of the
//   141us attn plateau. All else byte-identical to R7.

typedef __attribute__((ext_vector_type(4))) float  f32x4;
typedef __attribute__((ext_vector_type(8))) short  bf16x8;
typedef __attribute__((ext_vector_type(4))) short  s16x4;
typedef __attribute__((ext_vector_type(4))) unsigned u32x4;
typedef __attribute__((ext_vector_type(2))) unsigned u32x2;

__device__ __forceinline__ short f2bf(float f) {
    __hip_bfloat16 h = __float2bfloat16(f);
    return __builtin_bit_cast(short, h);
}

__device__ __forceinline__ unsigned cvt_pk_bf16(float lo, float hi) {
    unsigned w;
    asm("v_cvt_pk_bf16_f32 %0, %1, %2" : "=v"(w) : "v"(lo), "v"(hi));
    return w;
}

__device__ __forceinline__ void gll16(const short* g, short* l) {
    __builtin_amdgcn_global_load_lds(
        (const __attribute__((address_space(1))) void*)g,
        (__attribute__((address_space(3))) void*)l, 16, 0, 0);
}

// ---------------- conv_x ----------------
__global__ void conv_x_kernel(const float* __restrict__ x, short* __restrict__ xb) {
    int idx = blockIdx.x * 256 + threadIdx.x;
    f32x4 v = *reinterpret_cast<const f32x4*>(x + (size_t)idx * 4);
    s16x4 o;
    o[0] = f2bf(v[0]); o[1] = f2bf(v[1]); o[2] = f2bf(v[2]); o[3] = f2bf(v[3]);
    *reinterpret_cast<s16x4*>(xb + (size_t)idx * 4) = o;
}

// ---------------- wtrans ----------------
__global__ void wtrans_kernel(const float* __restrict__ W, short* __restrict__ Wt) {
    __shared__ float tile[64][65];
    int kb = blockIdx.x, nb = blockIdx.y;
    int t = threadIdx.x;
    int c4 = (t & 15) * 4;
    int r0 = t >> 4;
#pragma unroll
    for (int rr = 0; rr < 4; ++rr) {
        int kl = r0 + rr * 16;
        f32x4 v = *reinterpret_cast<const f32x4*>(W + (size_t)(kb * 64 + kl) * 3072 + nb * 64 + c4);
        tile[kl][c4 + 0] = v[0]; tile[kl][c4 + 1] = v[1];
        tile[kl][c4 + 2] = v[2]; tile[kl][c4 + 3] = v[3];
    }
    __syncthreads();
#pragma unroll
    for (int rr = 0; rr < 4; ++rr) {
        int nl = r0 + rr * 16;
        s16x4 o;
#pragma unroll
        for (int i = 0; i < 4; ++i) o[i] = f2bf(tile[c4 + i][nl]);
        *reinterpret_cast<s16x4*>(Wt + (size_t)(nb * 64 + nl) * 1024 + kb * 64 + c4) = o;
    }
}

// ---------------- qkv_gemm (R7 m97 structure; V written transposed) ----------------
__global__ __launch_bounds__(256) void qkv_gemm_kernel(
    const short* __restrict__ xb, const short* __restrict__ Wt,
    const float* __restrict__ bias,
    short* __restrict__ Qo, short* __restrict__ Ko, short* __restrict__ Vto)
{
    __shared__ short As[128 * 64];
    __shared__ short Bs[128 * 64];
    int tid = threadIdx.x;
    int wave = tid >> 6, lane = tid & 63, g = lane >> 4, lr = lane & 15;
    int wr = wave >> 1, wc = wave & 1;
    int bm = blockIdx.x, bn = blockIdx.y;

    f32x4 acc[4][4];
#pragma unroll
    for (int a = 0; a < 4; ++a)
#pragma unroll
        for (int b = 0; b < 4; ++b) acc[a][b] = (f32x4){0.f, 0.f, 0.f, 0.f};

    for (int k0 = 0; k0 < 1024; k0 += 64) {
#pragma unroll
        for (int j = 0; j < 4; ++j) {
            int c = j * 256 + tid;
            int row = c >> 3, cc = c & 7;
            int scc = (cc ^ (row & 7)) * 8;
            gll16(xb + (size_t)(bm * 128 + row) * 1024 + k0 + scc,
                  &As[(j * 256 + wave * 64) * 8]);
            gll16(Wt + (size_t)(bn * 128 + row) * 1024 + k0 + scc,
                  &Bs[(j * 256 + wave * 64) * 8]);
        }
        __syncthreads();

        bf16x8 af[2][4], bfr[2][4];
#pragma unroll
        for (int mt = 0; mt < 4; ++mt) {
            int row = wr * 64 + mt * 16 + lr;
            af[0][mt] = *reinterpret_cast<const bf16x8*>(&As[row * 64 + (((g    ) ^ (lr & 7)) * 8)]);
            af[1][mt] = *reinterpret_cast<const bf16x8*>(&As[row * 64 + (((g + 4) ^ (lr & 7)) * 8)]);
        }
#pragma unroll
        for (int nt = 0; nt < 4; ++nt) {
            int row = wc * 64 + nt * 16 + lr;
            bfr[0][nt] = *reinterpret_cast<const bf16x8*>(&Bs[row * 64 + (((g    ) ^ (lr & 7)) * 8)]);
            bfr[1][nt] = *reinterpret_cast<const bf16x8*>(&Bs[row * 64 + (((g + 4) ^ (lr & 7)) * 8)]);
        }
#pragma unroll
        for (int mt = 0; mt < 4; ++mt)
#pragma unroll
            for (int nt = 0; nt < 4; ++nt) {
                acc[mt][nt] = __builtin_amdgcn_mfma_f32_16x16x32_bf16(af[0][mt], bfr[0][nt], acc[mt][nt], 0, 0, 0);
                acc[mt][nt] = __builtin_amdgcn_mfma_f32_16x16x32_bf16(af[1][mt], bfr[1][nt], acc[mt][nt], 0, 0, 0);
            }
        __syncthreads();
    }

#pragma unroll
    for (int nt = 0; nt < 4; ++nt) {
        int n = bn * 128 + wc * 64 + nt * 16 + lr;
        float bv = bias[n];
        int which = n >> 10;
        int h = (n >> 6) & 15;
        int dd = n & 63;
#pragma unroll
        for (int mt = 0; mt < 4; ++mt) {
            int m0 = bm * 128 + wr * 64 + mt * 16 + g * 4;
            int bb = m0 >> 11, s0 = m0 & 2047;
            if (which == 2) {
                s16x4 o;
#pragma unroll
                for (int r = 0; r < 4; ++r) o[r] = f2bf(acc[mt][nt][r] + bv);
                *reinterpret_cast<s16x4*>(
                    Vto + ((size_t)(bb * 16 + h) * 64 + dd) * 2048 + s0) = o;
            } else {
                short* base = (which == 0) ? Qo : Ko;
#pragma unroll
                for (int r = 0; r < 4; ++r)
                    base[(((size_t)bb * 16 + h) * 2048 + s0 + r) * 64 + dd] =
                        f2bf(acc[mt][nt][r] + bv);
            }
        }
    }
}

// ---------------- attn ----------------
// grid 512; id = (bh&7) + 8*(qt + 16*(bh>>3)) -> XCD(id%8)==bh%8.
// 512 threads = 8 waves x 16 q-rows, KVBLK=64, dbuf K/V, 2-deep bias prefetch,
// COALESCED bias loads bounced through per-wave LDS.
__global__ __launch_bounds__(512, 4) void attn_kernel(
    const short* __restrict__ Qw, const short* __restrict__ Kw, const short* __restrict__ Vtw,
    const float* __restrict__ attnB, float* __restrict__ out)
{
    __shared__ short Ks [2][64 * 64];   // 16 KB
    __shared__ short Vts[2][64 * 64];   // 16 KB
    __shared__ short Ps [8][16 * 64];   // 16 KB
    __shared__ short Bb [8][16 * 64];   // 16 KB per-wave bias tile

    int id = blockIdx.x;
    int bh3 = id & 7;
    int qt  = (id >> 3) & 15;
    int bh  = ((id >> 7) << 3) | bh3;
    int b = bh >> 4, h = bh & 15;
    int tid = threadIdx.x;
    int wave = tid >> 6, lane = tid & 63, g = lane >> 4, lr = lane & 15;

    const short* Qb = Qw  + (size_t)bh * 2048 * 64;
    const short* Kb = Kw  + (size_t)bh * 2048 * 64;
    const short* Vb = Vtw + (size_t)bh * 64 * 2048;
    const float* Bp = attnB + (size_t)bh * 2048 * 2048;

    int qbase = qt * 128 + wave * 16;

    bf16x8 qf0, qf1;
    {
        const short* qp = Qb + (size_t)(qbase + lr) * 64 + g * 8;
        qf0 = *reinterpret_cast<const bf16x8*>(qp);
        qf1 = *reinterpret_cast<const bf16x8*>(qp + 32);
    }

    // coalesced bias pointer: lane covers row (lane>>4)+4i, cols (lane&15)*4..+3
    int brr = lane >> 4;           // 0..3
    int bc4 = (lane & 15) * 4;     // col base (floats)
    const float* Bcol = Bp + (size_t)(qbase + brr) * 2048 + bc4;
    // LDS bounce write geometry (per-wave, swizzled 16B chunks)
    int bchunk = bc4 >> 3;         // 0..7
    int bhalf  = (bc4 >> 2) & 1;

    f32x4 Os[4], Ob[4];
#pragma unroll
    for (int dt = 0; dt < 4; ++dt) { Os[dt] = (f32x4){0.f,0.f,0.f,0.f}; Ob[dt] = (f32x4){0.f,0.f,0.f,0.f}; }
    float lsum = 0.f;

#define STAGE_KV(buf, ktt) do {                                                   \
    int row = tid >> 3, cc = tid & 7;                                             \
    int scc = (cc ^ (row & 7)) * 8;                                               \
    gll16(Kb + (size_t)((ktt) * 64 + row) * 64 + scc,                             \
          &Ks[buf][wave * 512]);                                                  \
    gll16(Vb + (size_t)row * 2048 + (ktt) * 64 + scc,                             \
          &Vts[buf][wave * 512]);                                                 \
} while (0)

// coalesced: instr i reads rows qbase + brr + 4i (4 rows x 256B contiguous)
#define LOADB(d0, d1, d2, d3, ktt) do {                                           \
    const float* bp_ = Bcol + (size_t)(ktt) * 64;                                 \
    d0 = *reinterpret_cast<const f32x4*>(bp_);                                    \
    d1 = *reinterpret_cast<const f32x4*>(bp_ + 4 * 2048);                         \
    d2 = *reinterpret_cast<const f32x4*>(bp_ + 8 * 2048);                         \
    d3 = *reinterpret_cast<const f32x4*>(bp_ + 12 * 2048);                        \
} while (0)

// write 4 bf16 (one row each) to per-wave Bb, swizzled
#define BOUNCE_W(d0, d1, d2, d3) do {                                             \
    short* bw = &Bb[wave][0];                                                     \
    f32x4 dd_[4] = {d0, d1, d2, d3};                                              \
    _Pragma("unroll")                                                             \
    for (int i_ = 0; i_ < 4; ++i_) {                                              \
        int row_ = brr + 4 * i_;                                                  \
        u32x2 w_;                                                                 \
        w_[0] = cvt_pk_bf16(dd_[i_][0], dd_[i_][1]);                              \
        w_[1] = cvt_pk_bf16(dd_[i_][2], dd_[i_][3]);                              \
        *reinterpret_cast<u32x2*>(bw + row_ * 64 +                                \
            ((bchunk ^ (row_ & 7)) << 3) + bhalf * 4) = w_;                       \
    }                                                                             \
} while (0)

#define COMPUTE(cur, xb0, xb1) do {                                               \
    f32x4 S[4];                                                                   \
    __builtin_amdgcn_s_setprio(1);                                                \
    _Pragma("unroll")                                                             \
    for (int nt = 0; nt < 4; ++nt) {                                              \
        int row = nt * 16 + lr;                                                   \
        bf16x8 kf0 = *reinterpret_cast<const bf16x8*>(&Ks[cur][row * 64 + (((g    ) ^ (lr & 7)) * 8)]); \
        bf16x8 kf1 = *reinterpret_cast<const bf16x8*>(&Ks[cur][row * 64 + (((g + 4) ^ (lr & 7)) * 8)]); \
        f32x4 s = (f32x4){0.f,0.f,0.f,0.f};                                       \
        s = __builtin_amdgcn_mfma_f32_16x16x32_bf16(kf0, qf0, s, 0, 0, 0);        \
        s = __builtin_amdgcn_mfma_f32_16x16x32_bf16(kf1, qf1, s, 0, 0, 0);        \
        S[nt] = s;                                                                \
    }                                                                             \
    __builtin_amdgcn_s_setprio(0);                                                \
    _Pragma("unroll")                                                             \
    for (int nt = 0; nt < 4; ++nt)                                                \
        _Pragma("unroll")                                                         \
        for (int r = 0; r < 4; ++r) {                                             \
            float p = exp2f(S[nt][r] * 0.1803368801111f);                         \
            S[nt][r] = p;                                                         \
            lsum += p;                                                            \
        }                                                                         \
    short* psw = &Ps[wave][lr * 64];                                              \
    _Pragma("unroll")                                                             \
    for (int nt = 0; nt < 4; ++nt)                                                \
        _Pragma("unroll")                                                         \
        for (int rp = 0; rp < 2; ++rp) {                                          \
            unsigned w = cvt_pk_bf16(S[nt][2 * rp], S[nt][2 * rp + 1]);           \
            int kp = 8 * nt + 2 * g + rp;                                         \
            int bi = kp >> 2, off = kp & 3;                                       \
            *reinterpret_cast<unsigned*>(psw + ((bi ^ (lr & 7)) << 3) + off * 2) = w; \
        }                                                                         \
    bf16x8 pf0 = *reinterpret_cast<const bf16x8*>(&Ps[wave][lr * 64 + (((g    ) ^ (lr & 7)) * 8)]); \
    bf16x8 pf1 = *reinterpret_cast<const bf16x8*>(&Ps[wave][lr * 64 + (((g + 4) ^ (lr & 7)) * 8)]); \
    __builtin_amdgcn_s_setprio(1);                                                \
    _Pragma("unroll")                                                             \
    for (int dt = 0; dt < 4; ++dt) {                                              \
        int row = dt * 16 + lr;                                                   \
        bf16x8 v0 = *reinterpret_cast<const bf16x8*>(&Vts[cur][row * 64 + (((g    ) ^ (lr & 7)) * 8)]); \
        bf16x8 v1 = *reinterpret_cast<const bf16x8*>(&Vts[cur][row * 64 + (((g + 4) ^ (lr & 7)) * 8)]); \
        Os[dt] = __builtin_amdgcn_mfma_f32_16x16x32_bf16(pf0, v0, Os[dt], 0, 0, 0); \
        Os[dt] = __builtin_amdgcn_mfma_f32_16x16x32_bf16(pf1, v1, Os[dt], 0, 0, 0); \
        Ob[dt] = __builtin_amdgcn_mfma_f32_16x16x32_bf16(xb0, v0, Ob[dt], 0, 0, 0); \
        Ob[dt] = __builtin_amdgcn_mfma_f32_16x16x32_bf16(xb1, v1, Ob[dt], 0, 0, 0); \
    }                                                                             \
    __builtin_amdgcn_s_setprio(0);                                                \
} while (0)

// read back this wave's bias A-frags (written by BOUNCE_W this iter)
#define BREAD(xb0, xb1) do {                                                      \
    xb0 = *reinterpret_cast<const bf16x8*>(&Bb[wave][lr * 64 + (((g    ) ^ (lr & 7)) * 8)]); \
    xb1 = *reinterpret_cast<const bf16x8*>(&Bb[wave][lr * 64 + (((g + 4) ^ (lr & 7)) * 8)]); \
} while (0)

    f32x4 a0, a1, a2, a3, p0, p1, p2, p3;

    STAGE_KV(0, 0);
    __builtin_amdgcn_sched_barrier(0);
    LOADB(a0, a1, a2, a3, 0);
    LOADB(p0, p1, p2, p3, 1);
    __builtin_amdgcn_sched_barrier(0);
    asm volatile("s_waitcnt vmcnt(8)" ::: "memory");
    __builtin_amdgcn_s_barrier();
    __builtin_amdgcn_sched_barrier(0);

    for (int t = 0; t < 16; ++t) {
        // ==== even iter kt=2t, K/V buf0, bias set A ====
        {
            BOUNCE_W(a0, a1, a2, a3);                 // cvt + ds_write (wave-private)
            STAGE_KV(1, 2 * t + 1);
            __builtin_amdgcn_sched_barrier(0);
            if (t < 15) LOADB(a0, a1, a2, a3, 2 * t + 2);
            __builtin_amdgcn_sched_barrier(0);
            bf16x8 bbf0, bbf1;
            BREAD(bbf0, bbf1);                        // ds_read back in frag layout
            COMPUTE(0, bbf0, bbf1);
            if (t < 15) {
                asm volatile("s_waitcnt vmcnt(4)" ::: "memory");
            } else {
                asm volatile("s_waitcnt vmcnt(0)" ::: "memory");
            }
            __builtin_amdgcn_s_barrier();
            __builtin_amdgcn_sched_barrier(0);
        }
        // ==== odd iter kt=2t+1, K/V buf1, bias set P ====
        {
            BOUNCE_W(p0, p1, p2, p3);
            if (t < 15) {
                STAGE_KV(0, 2 * t + 2);
                __builtin_amdgcn_sched_barrier(0);
                LOADB(p0, p1, p2, p3, 2 * t + 3);
                __builtin_amdgcn_sched_barrier(0);
            }
            bf16x8 bbf0, bbf1;
            BREAD(bbf0, bbf1);
            COMPUTE(1, bbf0, bbf1);
            if (t < 15) {
                asm volatile("s_waitcnt vmcnt(4)" ::: "memory");
                __builtin_amdgcn_s_barrier();
                __builtin_amdgcn_sched_barrier(0);
            }
        }
    }
#undef STAGE_KV
#undef LOADB
#undef BOUNCE_W
#undef BREAD
#undef COMPUTE

    float l = lsum;
    l += __shfl_xor(l, 16);
    l += __shfl_xor(l, 32);
    float inv = 1.0f / l;
#pragma unroll
    for (int r = 0; r < 4; ++r) {
        float invr = __shfl(inv, g * 4 + r);
        int q = qbase + g * 4 + r;
#pragma unroll
        for (int dt = 0; dt < 4; ++dt) {
            int dcol = dt * 16 + lr;
            float v = Os[dt][r] * invr + Ob[dt][r];
            __builtin_nontemporal_store(v, &out[((size_t)(b * 2048 + q) * 16 + h) * 64 + dcol]);
        }
    }
}

extern "C" void kernel_launch(void* const* d_in, const int* in_sizes, int n_in,
                              void* d_out, int out_size, void* d_ws, size_t ws_size,
                              hipStream_t stream) {
    const float* x     = (const float*)d_in[0];
    const float* attnB = (const float*)d_in[1];
    const float* W     = (const float*)d_in[2];
    const float* bias  = (const float*)d_in[3];
    float* out = (float*)d_out;

    short* ws = (short*)d_ws;
    short* xb = ws;                // 4,194,304 shorts
    short* Wt = xb + 4194304;      // 3,145,728
    short* Q  = Wt + 3145728;      // 4,194,304
    short* K  = Q  + 4194304;      // 4,194,304
    short* Vt = K  + 4194304;      // 4,194,304

    conv_x_kernel<<<4096, 256, 0, stream>>>(x, xb);
    wtrans_kernel<<<dim3(16, 48), 256, 0, stream>>>(W, Wt);
    qkv_gemm_kernel<<<dim3(32, 24), 256, 0, stream>>>(xb, Wt, bias, Q, K, Vt);
    attn_kernel<<<512, 512, 0, stream>>>(Q, K, Vt, attnB, out);
}

// Round 12
// 206.632 us; speedup vs baseline: 1.3401x; 1.3401x over previous
//
#include <hip/hip_runtime.h>
#include <hip/hip_bf16.h>

// y = (softmax((xWq)(xWk)^T/8) + B) @ (xWv); b=2 s=2048 d=1024 h=16 hd=64
// conv_x -> wtrans -> qkv_gemm (m97 128^2 + LDS-staged coalesced Q/K epilogue,
//   V pre-transposed direct) -> attn (R7 verbatim, best measured: 141us).

typedef __attribute__((ext_vector_type(4))) float  f32x4;
typedef __attribute__((ext_vector_type(8))) short  bf16x8;
typedef __attribute__((ext_vector_type(4))) short  s16x4;
typedef __attribute__((ext_vector_type(4))) unsigned u32x4;

__device__ __forceinline__ short f2bf(float f) {
    __hip_bfloat16 h = __float2bfloat16(f);
    return __builtin_bit_cast(short, h);
}

__device__ __forceinline__ unsigned cvt_pk_bf16(float lo, float hi) {
    unsigned w;
    asm("v_cvt_pk_bf16_f32 %0, %1, %2" : "=v"(w) : "v"(lo), "v"(hi));
    return w;
}

__device__ __forceinline__ bf16x8 pack8(f32x4 a, f32x4 b) {
    u32x4 t = (u32x4){cvt_pk_bf16(a[0], a[1]), cvt_pk_bf16(a[2], a[3]),
                      cvt_pk_bf16(b[0], b[1]), cvt_pk_bf16(b[2], b[3])};
    return __builtin_bit_cast(bf16x8, t);
}

__device__ __forceinline__ void gll16(const short* g, short* l) {
    __builtin_amdgcn_global_load_lds(
        (const __attribute__((address_space(1))) void*)g,
        (__attribute__((address_space(3))) void*)l, 16, 0, 0);
}

// ---------------- conv_x ----------------
__global__ void conv_x_kernel(const float* __restrict__ x, short* __restrict__ xb) {
    int idx = blockIdx.x * 256 + threadIdx.x;
    f32x4 v = *reinterpret_cast<const f32x4*>(x + (size_t)idx * 4);
    s16x4 o;
    o[0] = f2bf(v[0]); o[1] = f2bf(v[1]); o[2] = f2bf(v[2]); o[3] = f2bf(v[3]);
    *reinterpret_cast<s16x4*>(xb + (size_t)idx * 4) = o;
}

// ---------------- wtrans ----------------
__global__ void wtrans_kernel(const float* __restrict__ W, short* __restrict__ Wt) {
    __shared__ float tile[64][65];
    int kb = blockIdx.x, nb = blockIdx.y;
    int t = threadIdx.x;
    int c4 = (t & 15) * 4;
    int r0 = t >> 4;
#pragma unroll
    for (int rr = 0; rr < 4; ++rr) {
        int kl = r0 + rr * 16;
        f32x4 v = *reinterpret_cast<const f32x4*>(W + (size_t)(kb * 64 + kl) * 3072 + nb * 64 + c4);
        tile[kl][c4 + 0] = v[0]; tile[kl][c4 + 1] = v[1];
        tile[kl][c4 + 2] = v[2]; tile[kl][c4 + 3] = v[3];
    }
    __syncthreads();
#pragma unroll
    for (int rr = 0; rr < 4; ++rr) {
        int nl = r0 + rr * 16;
        s16x4 o;
#pragma unroll
        for (int i = 0; i < 4; ++i) o[i] = f2bf(tile[c4 + i][nl]);
        *reinterpret_cast<s16x4*>(Wt + (size_t)(nb * 64 + nl) * 1024 + kb * 64 + c4) = o;
    }
}

// ---------------- qkv_gemm (m97; LDS-staged coalesced Q/K epilogue) ----------------
__global__ __launch_bounds__(256) void qkv_gemm_kernel(
    const short* __restrict__ xb, const short* __restrict__ Wt,
    const float* __restrict__ bias,
    short* __restrict__ Qo, short* __restrict__ Ko, short* __restrict__ Vto)
{
    __shared__ short smem[128 * 128];   // 32 KB: As(16K) | Bs(16K); reused as C-tile
    short* As = smem;
    short* Bs = smem + 128 * 64;

    int tid = threadIdx.x;
    int wave = tid >> 6, lane = tid & 63, g = lane >> 4, lr = lane & 15;
    int wr = wave >> 1, wc = wave & 1;
    int bm = blockIdx.x, bn = blockIdx.y;

    f32x4 acc[4][4];
#pragma unroll
    for (int a = 0; a < 4; ++a)
#pragma unroll
        for (int b = 0; b < 4; ++b) acc[a][b] = (f32x4){0.f, 0.f, 0.f, 0.f};

    for (int k0 = 0; k0 < 1024; k0 += 64) {
#pragma unroll
        for (int j = 0; j < 4; ++j) {
            int c = j * 256 + tid;
            int row = c >> 3, cc = c & 7;
            int scc = (cc ^ (row & 7)) * 8;
            gll16(xb + (size_t)(bm * 128 + row) * 1024 + k0 + scc,
                  &As[(j * 256 + wave * 64) * 8]);
            gll16(Wt + (size_t)(bn * 128 + row) * 1024 + k0 + scc,
                  &Bs[(j * 256 + wave * 64) * 8]);
        }
        __syncthreads();

        bf16x8 af[2][4], bfr[2][4];
#pragma unroll
        for (int mt = 0; mt < 4; ++mt) {
            int row = wr * 64 + mt * 16 + lr;
            af[0][mt] = *reinterpret_cast<const bf16x8*>(&As[row * 64 + (((g    ) ^ (lr & 7)) * 8)]);
            af[1][mt] = *reinterpret_cast<const bf16x8*>(&As[row * 64 + (((g + 4) ^ (lr & 7)) * 8)]);
        }
#pragma unroll
        for (int nt = 0; nt < 4; ++nt) {
            int row = wc * 64 + nt * 16 + lr;
            bfr[0][nt] = *reinterpret_cast<const bf16x8*>(&Bs[row * 64 + (((g    ) ^ (lr & 7)) * 8)]);
            bfr[1][nt] = *reinterpret_cast<const bf16x8*>(&Bs[row * 64 + (((g + 4) ^ (lr & 7)) * 8)]);
        }
#pragma unroll
        for (int mt = 0; mt < 4; ++mt)
#pragma unroll
            for (int nt = 0; nt < 4; ++nt) {
                acc[mt][nt] = __builtin_amdgcn_mfma_f32_16x16x32_bf16(af[0][mt], bfr[0][nt], acc[mt][nt], 0, 0, 0);
                acc[mt][nt] = __builtin_amdgcn_mfma_f32_16x16x32_bf16(af[1][mt], bfr[1][nt], acc[mt][nt], 0, 0, 0);
            }
        __syncthreads();
    }

    int which = bn >> 3;   // uniform per block (bn*128 never straddles a 1024 boundary)

    if (which == 2) {
        // V: direct transposed store Vt[bh][64][2048], s16x4 (4 contiguous s)
#pragma unroll
        for (int nt = 0; nt < 4; ++nt) {
            int n = bn * 128 + wc * 64 + nt * 16 + lr;
            float bv = bias[n];
            int h = (n >> 6) & 15;
            int dd = n & 63;
#pragma unroll
            for (int mt = 0; mt < 4; ++mt) {
                int m0 = bm * 128 + wr * 64 + mt * 16 + g * 4;
                int bb = m0 >> 11, s0 = m0 & 2047;
                s16x4 o;
#pragma unroll
                for (int r = 0; r < 4; ++r) o[r] = f2bf(acc[mt][nt][r] + bv);
                *reinterpret_cast<s16x4*>(
                    Vto + ((size_t)(bb * 16 + h) * 64 + dd) * 2048 + s0) = o;
            }
        }
    } else {
        // Q/K: stage C-tile (bias added) in LDS (chunk-XOR swizzle), then
        // fully-coalesced bf16x8 stores (8 lanes = 128B runs).
#pragma unroll
        for (int nt = 0; nt < 4; ++nt) {
            int col = wc * 64 + nt * 16 + lr;
            float bv = bias[bn * 128 + col];
            int ch = col >> 3, wi = col & 7;
#pragma unroll
            for (int mt = 0; mt < 4; ++mt)
#pragma unroll
                for (int r = 0; r < 4; ++r) {
                    int row = wr * 64 + mt * 16 + g * 4 + r;
                    smem[row * 128 + (((ch & 8) | ((ch & 7) ^ (row & 7))) << 3) + wi] =
                        f2bf(acc[mt][nt][r] + bv);
                }
        }
        __syncthreads();

        short* base = (which == 0) ? Qo : Ko;
#pragma unroll
        for (int it = 0; it < 8; ++it) {
            int idx = it * 256 + tid;          // 0..2047 = row(128) x chunk(16)
            int row = idx >> 4, ch = idx & 15;
            int swz = (ch & 8) | ((ch & 7) ^ (row & 7));
            bf16x8 v = *reinterpret_cast<const bf16x8*>(&smem[row * 128 + swz * 8]);
            int col8 = ch * 8;
            int h = (bn * 2 + (col8 >> 6)) & 15;
            int dd = col8 & 63;
            int m = bm * 128 + row, bb = m >> 11, s = m & 2047;
            *reinterpret_cast<bf16x8*>(
                &base[(((size_t)bb * 16 + h) * 2048 + s) * 64 + dd]) = v;
        }
    }
}

// ---------------- attn (R7 verbatim; measured 141us) ----------------
__global__ __launch_bounds__(512, 4) void attn_kernel(
    const short* __restrict__ Qw, const short* __restrict__ Kw, const short* __restrict__ Vtw,
    const float* __restrict__ attnB, float* __restrict__ out)
{
    __shared__ short Ks [2][64 * 64];
    __shared__ short Vts[2][64 * 64];
    __shared__ short Ps [8][16 * 64];

    int id = blockIdx.x;
    int bh3 = id & 7;
    int qt  = (id >> 3) & 15;
    int bh  = ((id >> 7) << 3) | bh3;
    int b = bh >> 4, h = bh & 15;
    int tid = threadIdx.x;
    int wave = tid >> 6, lane = tid & 63, g = lane >> 4, lr = lane & 15;

    const short* Qb = Qw  + (size_t)bh * 2048 * 64;
    const short* Kb = Kw  + (size_t)bh * 2048 * 64;
    const short* Vb = Vtw + (size_t)bh * 64 * 2048;
    const float* Bp = attnB + (size_t)bh * 2048 * 2048;

    int qbase = qt * 128 + wave * 16;

    bf16x8 qf0, qf1;
    {
        const short* qp = Qb + (size_t)(qbase + lr) * 64 + g * 8;
        qf0 = *reinterpret_cast<const bf16x8*>(qp);
        qf1 = *reinterpret_cast<const bf16x8*>(qp + 32);
    }
    const float* brow = Bp + (size_t)(qbase + lr) * 2048 + g * 8;

    f32x4 Os[4], Ob[4];
#pragma unroll
    for (int dt = 0; dt < 4; ++dt) { Os[dt] = (f32x4){0.f,0.f,0.f,0.f}; Ob[dt] = (f32x4){0.f,0.f,0.f,0.f}; }
    float lsum = 0.f;

#define STAGE_KV(buf, ktt) do {                                                   \
    int row = tid >> 3, cc = tid & 7;                                             \
    int scc = (cc ^ (row & 7)) * 8;                                               \
    gll16(Kb + (size_t)((ktt) * 64 + row) * 64 + scc,                             \
          &Ks[buf][wave * 512]);                                                  \
    gll16(Vb + (size_t)row * 2048 + (ktt) * 64 + scc,                             \
          &Vts[buf][wave * 512]);                                                 \
} while (0)

#define LOADB(d0, d1, d2, d3, ktt) do {                                           \
    const float* bp_ = brow + (size_t)(ktt) * 64;                                 \
    d0 = *reinterpret_cast<const f32x4*>(bp_);                                    \
    d1 = *reinterpret_cast<const f32x4*>(bp_ + 4);                                \
    d2 = *reinterpret_cast<const f32x4*>(bp_ + 32);                               \
    d3 = *reinterpret_cast<const f32x4*>(bp_ + 36);                               \
} while (0)

#define COMPUTE(cur, xb0, xb1) do {                                               \
    f32x4 S[4];                                                                   \
    __builtin_amdgcn_s_setprio(1);                                                \
    _Pragma("unroll")                                                             \
    for (int nt = 0; nt < 4; ++nt) {                                              \
        int row = nt * 16 + lr;                                                   \
        bf16x8 kf0 = *reinterpret_cast<const bf16x8*>(&Ks[cur][row * 64 + (((g    ) ^ (lr & 7)) * 8)]); \
        bf16x8 kf1 = *reinterpret_cast<const bf16x8*>(&Ks[cur][row * 64 + (((g + 4) ^ (lr & 7)) * 8)]); \
        f32x4 s = (f32x4){0.f,0.f,0.f,0.f};                                       \
        s = __builtin_amdgcn_mfma_f32_16x16x32_bf16(kf0, qf0, s, 0, 0, 0);        \
        s = __builtin_amdgcn_mfma_f32_16x16x32_bf16(kf1, qf1, s, 0, 0, 0);        \
        S[nt] = s;                                                                \
    }                                                                             \
    __builtin_amdgcn_s_setprio(0);                                                \
    _Pragma("unroll")                                                             \
    for (int nt = 0; nt < 4; ++nt)                                                \
        _Pragma("unroll")                                                         \
        for (int r = 0; r < 4; ++r) {                                             \
            float p = exp2f(S[nt][r] * 0.1803368801111f);                         \
            S[nt][r] = p;                                                         \
            lsum += p;                                                            \
        }                                                                         \
    short* psw = &Ps[wave][lr * 64];                                              \
    _Pragma("unroll")                                                             \
    for (int nt = 0; nt < 4; ++nt)                                                \
        _Pragma("unroll")                                                         \
        for (int rp = 0; rp < 2; ++rp) {                                          \
            unsigned w = cvt_pk_bf16(S[nt][2 * rp], S[nt][2 * rp + 1]);           \
            int kp = 8 * nt + 2 * g + rp;                                         \
            int bi = kp >> 2, off = kp & 3;                                       \
            *reinterpret_cast<unsigned*>(psw + ((bi ^ (lr & 7)) << 3) + off * 2) = w; \
        }                                                                         \
    bf16x8 pf0 = *reinterpret_cast<const bf16x8*>(&Ps[wave][lr * 64 + (((g    ) ^ (lr & 7)) * 8)]); \
    bf16x8 pf1 = *reinterpret_cast<const bf16x8*>(&Ps[wave][lr * 64 + (((g + 4) ^ (lr & 7)) * 8)]); \
    __builtin_amdgcn_s_setprio(1);                                                \
    _Pragma("unroll")                                                             \
    for (int dt = 0; dt < 4; ++dt) {                                              \
        int row = dt * 16 + lr;                                                   \
        bf16x8 v0 = *reinterpret_cast<const bf16x8*>(&Vts[cur][row * 64 + (((g    ) ^ (lr & 7)) * 8)]); \
        bf16x8 v1 = *reinterpret_cast<const bf16x8*>(&Vts[cur][row * 64 + (((g + 4) ^ (lr & 7)) * 8)]); \
        Os[dt] = __builtin_amdgcn_mfma_f32_16x16x32_bf16(pf0, v0, Os[dt], 0, 0, 0); \
        Os[dt] = __builtin_amdgcn_mfma_f32_16x16x32_bf16(pf1, v1, Os[dt], 0, 0, 0); \
        Ob[dt] = __builtin_amdgcn_mfma_f32_16x16x32_bf16(xb0, v0, Ob[dt], 0, 0, 0); \
        Ob[dt] = __builtin_amdgcn_mfma_f32_16x16x32_bf16(xb1, v1, Ob[dt], 0, 0, 0); \
    }                                                                             \
    __builtin_amdgcn_s_setprio(0);                                                \
} while (0)

    f32x4 a0, a1, a2, a3, p0, p1, p2, p3;

    STAGE_KV(0, 0);
    __builtin_amdgcn_sched_barrier(0);
    LOADB(a0, a1, a2, a3, 0);
    LOADB(p0, p1, p2, p3, 1);
    __builtin_amdgcn_sched_barrier(0);
    asm volatile("s_waitcnt vmcnt(8)" ::: "memory");
    __builtin_amdgcn_s_barrier();
    __builtin_amdgcn_sched_barrier(0);

    for (int t = 0; t < 16; ++t) {
        {
            bf16x8 bbf0 = pack8(a0, a1);
            bf16x8 bbf1 = pack8(a2, a3);
            STAGE_KV(1, 2 * t + 1);
            __builtin_amdgcn_sched_barrier(0);
            if (t < 15) LOADB(a0, a1, a2, a3, 2 * t + 2);
            __builtin_amdgcn_sched_barrier(0);
            COMPUTE(0, bbf0, bbf1);
            if (t < 15) {
                asm volatile("s_waitcnt vmcnt(4)" ::: "memory");
            } else {
                asm volatile("s_waitcnt vmcnt(0)" ::: "memory");
            }
            __builtin_amdgcn_s_barrier();
            __builtin_amdgcn_sched_barrier(0);
        }
        {
            bf16x8 bbf0 = pack8(p0, p1);
            bf16x8 bbf1 = pack8(p2, p3);
            if (t < 15) {
                STAGE_KV(0, 2 * t + 2);
                __builtin_amdgcn_sched_barrier(0);
                LOADB(p0, p1, p2, p3, 2 * t + 3);
                __builtin_amdgcn_sched_barrier(0);
            }
            COMPUTE(1, bbf0, bbf1);
            if (t < 15) {
                asm volatile("s_waitcnt vmcnt(4)" ::: "memory");
                __builtin_amdgcn_s_barrier();
                __builtin_amdgcn_sched_barrier(0);
            }
        }
    }
#undef STAGE_KV
#undef LOADB
#undef COMPUTE

    float l = lsum;
    l += __shfl_xor(l, 16);
    l += __shfl_xor(l, 32);
    float inv = 1.0f / l;
#pragma unroll
    for (int r = 0; r < 4; ++r) {
        float invr = __shfl(inv, g * 4 + r);
        int q = qbase + g * 4 + r;
#pragma unroll
        for (int dt = 0; dt < 4; ++dt) {
            int dcol = dt * 16 + lr;
            float v = Os[dt][r] * invr + Ob[dt][r];
            __builtin_nontemporal_store(v, &out[((size_t)(b * 2048 + q) * 16 + h) * 64 + dcol]);
        }
    }
}

extern "C" void kernel_launch(void* const* d_in, const int* in_sizes, int n_in,
                              void* d_out, int out_size, void* d_ws, size_t ws_size,
                              hipStream_t stream) {
    const float* x     = (const float*)d_in[0];
    const float* attnB = (const float*)d_in[1];
    const float* W     = (const float*)d_in[2];
    const float* bias  = (const float*)d_in[3];
    float* out = (float*)d_out;

    short* ws = (short*)d_ws;
    short* xb = ws;                // 4,194,304 shorts
    short* Wt = xb + 4194304;      // 3,145,728
    short* Q  = Wt + 3145728;      // 4,194,304
    short* K  = Q  + 4194304;      // 4,194,304
    short* Vt = K  + 4194304;      // 4,194,304

    conv_x_kernel<<<4096, 256, 0, stream>>>(x, xb);
    wtrans_kernel<<<dim3(16, 48), 256, 0, stream>>>(W, Wt);
    qkv_gemm_kernel<<<dim3(32, 24), 256, 0, stream>>>(xb, Wt, bias, Q, K, Vt);
    attn_kernel<<<512, 512, 0, stream>>>(Q, K, Vt, attnB, out);
}